// Round 2
// baseline (369.522 us; speedup 1.0000x reference)
//
#include <hip/hip_runtime.h>
#include <stdint.h>
#include <math.h>

#define NB 4
#define NH 16
#define NS 1024
#define ND 64
#define QT 64
#define KT 64
#define LDT 68           // padded row length (68*4B = 272B, 16B-aligned, stride 4 mod 32 banks)
#define NKT (NS/KT)      // 16
#define SCALE_F 10000.0f

// ---------------- threefry2x32, key = (0, 42)  (jax.random.key(42)) ----------------
__device__ __forceinline__ uint32_t rotl32(uint32_t x, int r){ return (x<<r)|(x>>(32-r)); }

__device__ __forceinline__ void threefry2x32(uint32_t x0, uint32_t x1,
                                             uint32_t &o0, uint32_t &o1){
  const uint32_t ks0 = 0u, ks1 = 42u, ks2 = 0x1BD11BF0u; // 0x1BD11BDA ^ 0 ^ 42
  x0 += ks0; x1 += ks1;
#define TFR(r) { x0 += x1; x1 = rotl32(x1,(r)); x1 ^= x0; }
  TFR(13) TFR(15) TFR(26) TFR(6)
  x0 += ks1; x1 += ks2 + 1u;
  TFR(17) TFR(29) TFR(16) TFR(24)
  x0 += ks2; x1 += ks0 + 2u;
  TFR(13) TFR(15) TFR(26) TFR(6)
  x0 += ks0; x1 += ks1 + 3u;
  TFR(17) TFR(29) TFR(16) TFR(24)
  x0 += ks1; x1 += ks2 + 4u;
  TFR(13) TFR(15) TFR(26) TFR(6)
  x0 += ks2; x1 += ks0 + 5u;
#undef TFR
  o0 = x0; o1 = x1;
}

// JAX partitionable threefry (default since jax 0.4.30):
//   bits(i) = out0 ^ out1 of threefry2x32(key, (hi64(i), lo64(i))) = threefry(0, i)
//   keep iff jax uniform(bits) < 0.9f  ⇔  (bits>>9) < 0x733333 (= 7549747)
__device__ __forceinline__ uint32_t keep_flat(uint32_t flat){
  uint32_t o0, o1;
  threefry2x32(0u, flat, o0, o1);
  return ((o0 ^ o1) >> 9) < 0x733333u ? 1u : 0u;
}

// Packed dropout mask: word w covers flat indices [32w, 32w+32), bit j = flat 32w+j.
// One thread = one element; wave-wide ballot packs 64 bits; lane 0 stores 2 words.
__global__ __launch_bounds__(256) void mask_kernel(uint32_t* __restrict__ mask){
  uint32_t gid = blockIdx.x * 256u + threadIdx.x;     // [0, 2^26)
  uint64_t b = __ballot(keep_flat(gid) != 0u);
  if ((threadIdx.x & 63u) == 0u) {
    uint32_t widx = gid >> 5;                         // wave-aligned -> even
    *(uint2*)&mask[widx] = make_uint2((uint32_t)b, (uint32_t)(b >> 32));
  }
}

__device__ __forceinline__ void ld4(float d[4], const float* p){
  float4 v = *(const float4*)p;
  d[0]=v.x; d[1]=v.y; d[2]=v.z; d[3]=v.w;
}

// Flash-style fp32 attention. Block = one (b,h) x 64-row Q tile. 256 threads:
// rg = tid>>4 owns 4 q-rows, cg = tid&15 owns 4 k-cols (QK phase) / 4 d-cols (PV phase).
template<int USE_MASK>
__global__ __launch_bounds__(256, 2) void attn_kernel(
    const float* __restrict__ Qg, const float* __restrict__ Kg,
    const float* __restrict__ Vg, const uint32_t* __restrict__ maskbuf,
    float* __restrict__ Og)
{
  __shared__ float Qt[ND][LDT];   // Qt[d][q]   (transposed)
  __shared__ float Kt[ND][LDT];   // Kt[d][k]   (transposed); reused as Pt[k][q] after QK
  __shared__ float Vs[KT][LDT];   // Vs[k][d]   (row-major)

  const int tid = threadIdx.x;
  const int bh  = blockIdx.x >> 4;       // consecutive blocks share (b,h) -> K/V L2 reuse
  const int qt  = blockIdx.x & 15;
  const int qbase = qt * QT;
  const int rg = tid >> 4;
  const int cg = tid & 15;
  const int q0 = rg * 4;
  const int k0 = cg * 4;
  const int d0 = cg * 4;

  // ---- load Q tile (coalesced float4 global read, transposed scalar LDS store)
  {
    const float* src = Qg + ((size_t)bh*NS + qbase)*ND;
    #pragma unroll
    for (int r = 0; r < 4; ++r) {
      int f = tid + 256*r;
      int row = f >> 4;
      int dq = (f & 15) * 4;
      float4 v = *(const float4*)(src + row*ND + dq);
      Qt[dq+0][row] = v.x; Qt[dq+1][row] = v.y;
      Qt[dq+2][row] = v.z; Qt[dq+3][row] = v.w;
    }
  }

  float Oa[4][4] = {};
  float m_run[4] = {-INFINITY,-INFINITY,-INFINITY,-INFINITY};
  float l_run[4] = {0.f,0.f,0.f,0.f};
  const uint32_t rowflat0 = (uint32_t)(bh*NS + qbase + q0);

  for (int ktile = 0; ktile < NKT; ++ktile) {
    __syncthreads();   // A: prior PV reads of Kt(=Pt)/Vs done
    {
      const float* srcK = Kg + ((size_t)bh*NS + ktile*KT)*ND;
      const float* srcV = Vg + ((size_t)bh*NS + ktile*KT)*ND;
      #pragma unroll
      for (int r = 0; r < 4; ++r) {
        int f = tid + 256*r;
        int row = f >> 4;
        int dq = (f & 15) * 4;
        float4 kv = *(const float4*)(srcK + row*ND + dq);
        Kt[dq+0][row] = kv.x; Kt[dq+1][row] = kv.y;
        Kt[dq+2][row] = kv.z; Kt[dq+3][row] = kv.w;
        *(float4*)&Vs[row][dq] = *(const float4*)(srcV + row*ND + dq);
      }
    }
    __syncthreads();   // B: tiles ready

    // ---- QK^T: s[i][j] = Q[q0+i] . K[k0+j]  (outer-product over d, b128 LDS reads)
    float s[4][4] = {};
    #pragma unroll 8
    for (int d = 0; d < ND; ++d) {
      float qv[4], kv[4];
      ld4(qv, &Qt[d][q0]);
      ld4(kv, &Kt[d][k0]);
      #pragma unroll
      for (int i=0;i<4;++i)
        #pragma unroll
        for (int j=0;j<4;++j)
          s[i][j] = fmaf(qv[i], kv[j], s[i][j]);
    }

    // ---- scale + online softmax (row stats across the 16 cg lanes)
    float alpha[4];
    #pragma unroll
    for (int i=0;i<4;++i) {
      #pragma unroll
      for (int j=0;j<4;++j) s[i][j] *= SCALE_F;
      float tm = fmaxf(fmaxf(s[i][0],s[i][1]), fmaxf(s[i][2],s[i][3]));
      #pragma unroll
      for (int off=1; off<16; off<<=1)
        tm = fmaxf(tm, __shfl_xor(tm, off));
      float mnew = fmaxf(m_run[i], tm);
      alpha[i] = __expf(m_run[i] - mnew);   // 0 on first tile (-inf)
      m_run[i] = mnew;
      float ps = 0.f;
      #pragma unroll
      for (int j=0;j<4;++j) { s[i][j] = __expf(s[i][j] - mnew); ps += s[i][j]; }
      #pragma unroll
      for (int off=1; off<16; off<<=1)
        ps += __shfl_xor(ps, off);
      l_run[i] = l_run[i]*alpha[i] + ps;
      #pragma unroll
      for (int j=0;j<4;++j) Oa[i][j] *= alpha[i];
    }

    __syncthreads();   // C: all QK reads of Kt done; safe to overwrite as Pt
    float (*Pt)[LDT] = Kt;   // Pt[k][q]

    // ---- dropout mask + stage P transposed
    #pragma unroll
    for (int i=0;i<4;++i) {
      uint32_t kb;
      if (USE_MASK) {
        uint32_t wrd = maskbuf[(rowflat0 + (uint32_t)i)*(NS/32)
                               + (uint32_t)(ktile*(KT/32) + (k0 >> 5))];
        kb = (wrd >> (k0 & 31)) & 0xFu;
      } else {
        kb = 0u;
        uint32_t fb = (rowflat0 + (uint32_t)i)*NS + (uint32_t)(ktile*KT + k0);
        #pragma unroll
        for (int j=0;j<4;++j)
          kb |= keep_flat(fb + (uint32_t)j) << j;
      }
      #pragma unroll
      for (int j=0;j<4;++j)
        Pt[k0+j][q0+i] = ((kb >> j) & 1u) ? s[i][j] : 0.f;
    }
    __syncthreads();   // D: Pt ready

    // ---- PV: Oa[i][j] += sum_c P[q0+i][c] * V[c][d0+j]
    #pragma unroll 8
    for (int c = 0; c < KT; ++c) {
      float pv[4], vv[4];
      ld4(pv, &Pt[c][q0]);
      ld4(vv, &Vs[c][d0]);
      #pragma unroll
      for (int i=0;i<4;++i)
        #pragma unroll
        for (int j=0;j<4;++j)
          Oa[i][j] = fmaf(pv[i], vv[j], Oa[i][j]);
    }
  }

  // ---- epilogue: / l  and  / (1-p)
  const float inv_keep = 1.0f / 0.9f;
  #pragma unroll
  for (int i=0;i<4;++i) {
    float sc = inv_keep / l_run[i];
    float4 o;
    o.x = Oa[i][0]*sc; o.y = Oa[i][1]*sc;
    o.z = Oa[i][2]*sc; o.w = Oa[i][3]*sc;
    *(float4*)(Og + ((size_t)bh*NS + qbase + q0 + i)*ND + d0) = o;
  }
}

extern "C" void kernel_launch(void* const* d_in, const int* in_sizes, int n_in,
                              void* d_out, int out_size, void* d_ws, size_t ws_size,
                              hipStream_t stream) {
  const float* x1  = (const float*)d_in[0];   // Q
  const float* kw  = (const float*)d_in[1];   // K
  const float* val = (const float*)d_in[2];   // V
  float* out = (float*)d_out;

  const size_t mask_bytes = (size_t)(1u<<23);  // 2^26 bits = 8 MB
  if (ws_size >= mask_bytes) {
    uint32_t* mask = (uint32_t*)d_ws;
    mask_kernel<<<dim3(1u<<18), dim3(256), 0, stream>>>(mask);
    attn_kernel<1><<<dim3(NB*NH*(NS/QT)), dim3(256), 0, stream>>>(x1, kw, val, mask, out);
  } else {
    attn_kernel<0><<<dim3(NB*NH*(NS/QT)), dim3(256), 0, stream>>>(x1, kw, val, nullptr, out);
  }
}

// Round 4
// 222.667 us; speedup vs baseline: 1.6595x; 1.6595x over previous
//
#include <hip/hip_runtime.h>
#include <stdint.h>
#include <math.h>

#define NB 4
#define NH 16
#define NS 1024
#define ND 64
#define QT 64            // q rows per block
#define KT 64            // k cols per tile
#define NKT (NS/KT)      // 16
#define LDH 72           // f16 row pad: 144B rows -> 16B-aligned b128 frag reads
#define SCALE_F 10000.0f

typedef _Float16 half8 __attribute__((ext_vector_type(8)));
typedef _Float16 half4 __attribute__((ext_vector_type(4)));
typedef float    f32x4 __attribute__((ext_vector_type(4)));

// ---------------- threefry2x32, key = (0, 42) ----------------
__device__ __forceinline__ void threefry2x32(uint32_t x0, uint32_t x1,
                                             uint32_t &o0, uint32_t &o1){
  const uint32_t ks0 = 0u, ks1 = 42u, ks2 = 0x1BD11BF0u; // 0x1BD11BDA ^ 0 ^ 42
  x0 += ks0; x1 += ks1;
#define TFR(r) { x0 += x1; x1 = __builtin_rotateleft32(x1,(r)); x1 ^= x0; }
  TFR(13) TFR(15) TFR(26) TFR(6)
  x0 += ks1; x1 += ks2 + 1u;
  TFR(17) TFR(29) TFR(16) TFR(24)
  x0 += ks2; x1 += ks0 + 2u;
  TFR(13) TFR(15) TFR(26) TFR(6)
  x0 += ks0; x1 += ks1 + 3u;
  TFR(17) TFR(29) TFR(16) TFR(24)
  x0 += ks1; x1 += ks2 + 4u;
  TFR(13) TFR(15) TFR(26) TFR(6)
  x0 += ks2; x1 += ks0 + 5u;
#undef TFR
  o0 = x0; o1 = x1;
}

// JAX partitionable threefry: bits(i) = o0^o1 of threefry(key, (0, i));
// keep iff (bits>>9) < 0x733333  (uniform < 0.9)
__device__ __forceinline__ uint32_t keep_flat(uint32_t flat){
  uint32_t o0, o1;
  threefry2x32(0u, flat, o0, o1);
  return ((o0 ^ o1) >> 9) < 0x733333u ? 1u : 0u;
}

__global__ __launch_bounds__(256) void mask_kernel(uint32_t* __restrict__ mask){
  uint32_t gid = blockIdx.x * 256u + threadIdx.x;     // [0, 2^26)
  uint64_t b = __ballot(keep_flat(gid) != 0u);
  if ((threadIdx.x & 63u) == 0u) {
    uint32_t widx = gid >> 5;                         // wave-aligned -> even
    *(uint2*)&mask[widx] = make_uint2((uint32_t)b, (uint32_t)(b >> 32));
  }
}

// MFMA flash attention. Block = (b,h) x 64-row Q tile; 4 waves x 16 q-rows.
// QK^T: fp16 2-term split (3 MFMA products) -> fp32 scores; PV: plain fp16 MFMA.
// A/B frag k-map assumption is permutation-safe (same map used for both operands).
template<int USE_MASK>
__global__ __launch_bounds__(256, 3) void attn_mfma(
    const float* __restrict__ Qg, const float* __restrict__ Kg,
    const float* __restrict__ Vg, const uint32_t* __restrict__ maskbuf,
    float* __restrict__ Og)
{
  __shared__ _Float16 Khi[KT][LDH];       // K hi parts, row-major [kc][d]
  __shared__ _Float16 Klo[KT][LDH];       // K lo parts
  __shared__ _Float16 Vt [ND][LDH];       // V transposed [d][kc]
  __shared__ _Float16 Pl [4][16][LDH];    // per-wave P [q][kc] (fp16, post-dropout)

  const int tid  = threadIdx.x;
  const int wid  = tid >> 6;
  const int lane = tid & 63;
  const int lhi  = lane >> 4;     // 0..3
  const int llo  = lane & 15;

  // bijective XCD swizzle: 1024 blocks, 8 XCDs, 128 contiguous work items each
  const int swz = (blockIdx.x & 7) * 128 + (blockIdx.x >> 3);
  const int bh  = swz >> 4;
  const int qt  = swz & 15;

  // ---- Q A-fragments (held in registers for the whole kernel), hi/lo split
  half8 qhi[2], qlo[2];
  {
    const float* qsrc = Qg + ((size_t)bh*NS + qt*QT + wid*16 + llo)*ND;
    #pragma unroll
    for (int ks = 0; ks < 2; ++ks) {
      const float* p = qsrc + ks*32 + lhi*8;
      float4 a = *(const float4*)p;
      float4 b = *(const float4*)(p + 4);
      float v[8] = {a.x,a.y,a.z,a.w,b.x,b.y,b.z,b.w};
      #pragma unroll
      for (int j = 0; j < 8; ++j) {
        _Float16 h = (_Float16)v[j];
        _Float16 l = (_Float16)(v[j] - (float)h);
        qhi[ks][j] = h;
        qlo[ks][j] = l;
      }
    }
  }

  f32x4 Oacc[4];
  #pragma unroll
  for (int nt=0;nt<4;++nt){ Oacc[nt][0]=0.f;Oacc[nt][1]=0.f;Oacc[nt][2]=0.f;Oacc[nt][3]=0.f; }
  float m_run[4] = {-INFINITY,-INFINITY,-INFINITY,-INFINITY};
  float l_run[4] = {0.f,0.f,0.f,0.f};
  const uint32_t rowflat_base = (uint32_t)(bh*NS + qt*QT + wid*16);

  for (int kt = 0; kt < NKT; ++kt) {
    __syncthreads();   // prior tile's LDS reads (K frags, Vt) complete
    {
      const float* srcK = Kg + ((size_t)bh*NS + kt*KT)*ND;
      const float* srcV = Vg + ((size_t)bh*NS + kt*KT)*ND;
      #pragma unroll
      for (int r = 0; r < 4; ++r) {
        int f   = tid + 256*r;
        int row = f >> 4;           // kc 0..63
        int dq  = (f & 15) * 4;     // d
        float4 kv = *(const float4*)(srcK + row*ND + dq);
        half4 h4, l4;
        float vals[4] = {kv.x, kv.y, kv.z, kv.w};
        #pragma unroll
        for (int j = 0; j < 4; ++j) {
          _Float16 h = (_Float16)vals[j];
          _Float16 l = (_Float16)(vals[j] - (float)h);
          h4[j] = h;
          l4[j] = l;
        }
        *(half4*)&Khi[row][dq] = h4;   // 8B vector LDS writes
        *(half4*)&Klo[row][dq] = l4;
        float4 vv = *(const float4*)(srcV + row*ND + dq);
        Vt[dq+0][row] = (_Float16)vv.x;   // transposed scalar writes (conflicted; measured)
        Vt[dq+1][row] = (_Float16)vv.y;
        Vt[dq+2][row] = (_Float16)vv.z;
        Vt[dq+3][row] = (_Float16)vv.w;
      }
    }
    __syncthreads();   // tiles ready

    // ---- QK^T via 3-product fp16 split; acc fp32
    f32x4 S[4];
    #pragma unroll
    for (int nt=0;nt<4;++nt){ S[nt][0]=0.f;S[nt][1]=0.f;S[nt][2]=0.f;S[nt][3]=0.f; }
    #pragma unroll
    for (int ks = 0; ks < 2; ++ks) {
      #pragma unroll
      for (int nt = 0; nt < 4; ++nt) {
        const int kr = nt*16 + llo;         // K row (kc), B-frag n = lane&15
        const int kd = ks*32 + lhi*8;       // k offset (d)
        half8 bh_ = *(const half8*)&Khi[kr][kd];
        half8 bl_ = *(const half8*)&Klo[kr][kd];
        S[nt] = __builtin_amdgcn_mfma_f32_16x16x32_f16(qhi[ks], bh_, S[nt], 0, 0, 0);
        S[nt] = __builtin_amdgcn_mfma_f32_16x16x32_f16(qlo[ks], bh_, S[nt], 0, 0, 0);
        S[nt] = __builtin_amdgcn_mfma_f32_16x16x32_f16(qhi[ks], bl_, S[nt], 0, 0, 0);
      }
    }

    // ---- scale + online softmax (C-layout: row = 4*lhi+reg, col = nt*16+llo)
    float alpha[4];
    #pragma unroll
    for (int reg = 0; reg < 4; ++reg) {
      #pragma unroll
      for (int nt = 0; nt < 4; ++nt) S[nt][reg] *= SCALE_F;
      float tm = fmaxf(fmaxf(S[0][reg], S[1][reg]), fmaxf(S[2][reg], S[3][reg]));
      #pragma unroll
      for (int off = 1; off < 16; off <<= 1) tm = fmaxf(tm, __shfl_xor(tm, off));
      float mnew = fmaxf(m_run[reg], tm);
      float al   = __expf(m_run[reg] - mnew);
      m_run[reg] = mnew;
      float ps = 0.f;
      #pragma unroll
      for (int nt = 0; nt < 4; ++nt) {
        float p = __expf(S[nt][reg] - mnew);
        S[nt][reg] = p;
        ps += p;
      }
      #pragma unroll
      for (int off = 1; off < 16; off <<= 1) ps += __shfl_xor(ps, off);
      l_run[reg] = l_run[reg]*al + ps;
      alpha[reg] = al;
    }
    #pragma unroll
    for (int nt = 0; nt < 4; ++nt)
      #pragma unroll
      for (int reg = 0; reg < 4; ++reg) Oacc[nt][reg] *= alpha[reg];

    // ---- dropout + stage P (fp16) into per-wave LDS
    #pragma unroll
    for (int reg = 0; reg < 4; ++reg) {
      const int ql = lhi*4 + reg;
      if (USE_MASK) {
        uint64_t w = *(const uint64_t*)(maskbuf + (size_t)(rowflat_base + ql)*32 + 2*kt);
        #pragma unroll
        for (int nt = 0; nt < 4; ++nt) {
          float p = ((w >> (nt*16 + llo)) & 1ull) ? S[nt][reg] : 0.f;
          Pl[wid][ql][nt*16 + llo] = (_Float16)p;
        }
      } else {
        uint32_t fb = (rowflat_base + ql)*NS + (uint32_t)(kt*KT + llo);
        #pragma unroll
        for (int nt = 0; nt < 4; ++nt) {
          float p = keep_flat(fb + nt*16) ? S[nt][reg] : 0.f;
          Pl[wid][ql][nt*16 + llo] = (_Float16)p;
        }
      }
    }

    // ---- PV: O += P(16x64) * V(64x64), fp16 MFMA (same k-map for A and B)
    #pragma unroll
    for (int ks = 0; ks < 2; ++ks) {
      half8 pa = *(const half8*)&Pl[wid][llo][ks*32 + lhi*8];
      #pragma unroll
      for (int nt = 0; nt < 4; ++nt) {
        half8 vb = *(const half8*)&Vt[nt*16 + llo][ks*32 + lhi*8];
        Oacc[nt] = __builtin_amdgcn_mfma_f32_16x16x32_f16(pa, vb, Oacc[nt], 0, 0, 0);
      }
    }
  }

  // ---- epilogue: / l_run and / (1-p)
  float sc[4];
  #pragma unroll
  for (int reg = 0; reg < 4; ++reg) sc[reg] = (1.0f/0.9f) / l_run[reg];
  #pragma unroll
  for (int reg = 0; reg < 4; ++reg) {
    const size_t rowoff = ((size_t)bh*NS + qt*QT + wid*16 + lhi*4 + reg)*ND;
    #pragma unroll
    for (int nt = 0; nt < 4; ++nt)
      Og[rowoff + nt*16 + llo] = Oacc[nt][reg] * sc[reg];
  }
}

extern "C" void kernel_launch(void* const* d_in, const int* in_sizes, int n_in,
                              void* d_out, int out_size, void* d_ws, size_t ws_size,
                              hipStream_t stream) {
  const float* x1  = (const float*)d_in[0];   // Q
  const float* kw  = (const float*)d_in[1];   // K
  const float* val = (const float*)d_in[2];   // V
  float* out = (float*)d_out;

  const size_t mask_bytes = (size_t)(1u<<23);  // 2^26 bits = 8 MB
  if (ws_size >= mask_bytes) {
    uint32_t* mask = (uint32_t*)d_ws;
    mask_kernel<<<dim3(1u<<18), dim3(256), 0, stream>>>(mask);
    attn_mfma<1><<<dim3(NB*NH*(NS/QT)), dim3(256), 0, stream>>>(x1, kw, val, mask, out);
  } else {
    attn_mfma<0><<<dim3(NB*NH*(NS/QT)), dim3(256), 0, stream>>>(x1, kw, val, nullptr, out);
  }
}